// Round 8
// baseline (426.717 us; speedup 1.0000x reference)
//
#include <hip/hip_runtime.h>
#include <hip/hip_bf16.h>

// Problem constants
#define BB   64
#define CIN  3
#define HH   224
#define WW   224
#define C1   32
#define H1   112
#define W1   112
#define C2   64
#define H2   56
#define W2   56
#define FEATN 64
#define OUTN 1024
#define K3TOT (FEATN*FEATN*FEATN)   // 262144

typedef __bf16 bf16x8 __attribute__((ext_vector_type(8)));
typedef float  f32x4  __attribute__((ext_vector_type(4)));
typedef unsigned int u32;

__device__ __forceinline__ void gload_lds16(const void* g, void* l) {
  __builtin_amdgcn_global_load_lds((const __attribute__((address_space(1))) u32*)g,
                                   (__attribute__((address_space(3))) u32*)l, 16, 0, 0);
}

// ---- halo: zero the 1-px border ring of h1T (64 x 114 x 114 x 32 bf16) ------
__global__ __launch_bounds__(256) void halo_kernel(__bf16* __restrict__ h1T) {
    int t = blockIdx.x * 256 + threadIdx.x;          // 64*452 = 28928
    if (t >= 64 * 452) return;
    int b = t / 452, s = t - b * 452;
    int row, col;
    if      (s < 114) { row = 0;        col = s; }
    else if (s < 228) { row = 113;      col = s - 114; }
    else if (s < 340) { row = s - 227;  col = 0; }     // rows 1..112
    else              { row = s - 339;  col = 113; }   // rows 1..112
    __bf16* p = h1T + (((size_t)b * 114 + row) * 114 + col) * 32;
    bf16x8 z = {};
    #pragma unroll
    for (int k = 0; k < 4; ++k) *(bf16x8*)(p + k * 8) = z;
}

// ---- w2frag: B-fragment-ready bf16 layout [j][q][lane][8] --------------------
__global__ __launch_bounds__(256) void w2frag_kernel(const float* __restrict__ w2,
        __bf16* __restrict__ wf) {
    int t = blockIdx.x * 256 + threadIdx.x;          // 18432
    if (t >= 4 * 9 * 64 * 8) return;
    int e    = t & 7;
    int lane = (t >> 3) & 63;
    int q    = (t >> 9) % 9;
    int j    = t / 4608;
    int oc = j * 16 + (lane & 15);
    int c  = (lane >> 4) * 8 + e;
    wf[t] = (__bf16)w2[(oc * C1 + c) * 9 + q];
}

// ---------------- conv1: (64,3,224,224) -> relu -> h1T channels-last bf16 -----
__global__ __launch_bounds__(256) void conv1_kernel(const float* __restrict__ x,
        const float* __restrict__ w1, const float* __restrict__ b1,
        __bf16* __restrict__ h1T) {
    int pos = blockIdx.x * 256 + threadIdx.x;        // 64*112*112 = 802816
    int b   = pos / (H1 * W1);
    int rem = pos - b * (H1 * W1);
    int oy  = rem / W1;
    int ox  = rem - oy * W1;
    int iy0 = oy * 2 - 1, ix0 = ox * 2 - 1;

    float win[27];
    #pragma unroll
    for (int c = 0; c < CIN; ++c)
      #pragma unroll
      for (int dy = 0; dy < 3; ++dy)
        #pragma unroll
        for (int dx = 0; dx < 3; ++dx) {
          int iy = iy0 + dy, ix = ix0 + dx;
          bool ok = (iy >= 0) & (iy < HH) & (ix >= 0) & (ix < WW);
          win[c*9 + dy*3 + dx] = ok ? x[((b*CIN + c)*HH + iy)*WW + ix] : 0.f;
        }

    float acc[32];
    #pragma unroll
    for (int oc = 0; oc < C1; ++oc) acc[oc] = b1[oc];
    #pragma unroll
    for (int q = 0; q < 27; ++q) {
      float wv = win[q];
      #pragma unroll
      for (int oc = 0; oc < C1; ++oc)
        acc[oc] = fmaf(w1[oc*27 + q], wv, acc[oc]);
    }

    bf16x8 outv[4];
    #pragma unroll
    for (int k = 0; k < 32; ++k)
      outv[k >> 3][k & 7] = (__bf16)fmaxf(acc[k], 0.f);
    __bf16* dst = h1T + (((size_t)b * 114 + oy + 1) * 114 + ox + 1) * 32;
    #pragma unroll
    for (int k = 0; k < 4; ++k) *(bf16x8*)(dst + k * 8) = outv[k];
}

// ---------------- conv2: implicit-GEMM MFMA, M=128/block, N=64, K=9x32 --------
__global__ __launch_bounds__(256) void conv2_kernel(const __bf16* __restrict__ h1T,
        const __bf16* __restrict__ wf, const float* __restrict__ b2,
        float* __restrict__ h2) {
    __shared__ __align__(16) char tile[2304 * 16];   // 36864 B (2280 real + pad)
    int t = threadIdx.x;
    int bid = blockIdx.x;                            // 64*28 = 1792
    int b  = bid / 28;
    int yt = bid - b * 28;
    int y0 = yt * 2;
    int w = t >> 6, lane = t & 63, l15 = lane & 15, l4 = lane >> 4;

    // ---- stage 5x114 sites (64B each) via gload_lds, 9 issues/wave
    const char* src_base = (const char*)(h1T + ((size_t)b * 114 + 2 * y0) * 114 * 32);
    #pragma unroll
    for (int i = 0; i < 9; ++i) {
      int g = (w * 9 + i) * 64 + lane;
      int site = g >> 2; site = site < 569 ? site : 569;
      int qp = g & 3;
      int r5 = site / 114;
      int col = site - r5 * 114;
      int ql = (qp - col) & 3;
      gload_lds16(src_base + (size_t)site * 64 + ql * 16, tile + (size_t)g * 16);
    }
    __syncthreads();

    // per-wave output tiles: mt = 2w+p, p in {0,1}
    int sbase[2], urot[2];
    #pragma unroll
    for (int p = 0; p < 2; ++p) {
      int mt = 2 * w + p;
      int yl = mt >> 2;
      int xl = ((mt & 3) << 4) + l15;
      int xe = xl < 55 ? xl : 55;                    // clamp padding lanes
      sbase[p] = ((yl * 2) * 114 + 2 * xe) * 64;
      urot[p]  = (l4 + 2 * xe) & 3;
    }

    f32x4 acc[2][4];
    #pragma unroll
    for (int p = 0; p < 2; ++p)
      #pragma unroll
      for (int j = 0; j < 4; ++j) acc[p][j] = (f32x4){0.f, 0.f, 0.f, 0.f};

    #pragma unroll
    for (int q = 0; q < 9; ++q) {
      int dy = q / 3, dx = q % 3;
      bf16x8 bw[4];
      #pragma unroll
      for (int j = 0; j < 4; ++j)
        bw[j] = *(const bf16x8*)(wf + ((j * 9 + q) * 64 + lane) * 8);
      bf16x8 af[2];
      #pragma unroll
      for (int p = 0; p < 2; ++p) {
        int addr = sbase[p] + (dy * 114 + dx) * 64 + (((urot[p] + dx) & 3) << 4);
        af[p] = *(const bf16x8*)(tile + addr);
      }
      #pragma unroll
      for (int p = 0; p < 2; ++p)
        #pragma unroll
        for (int j = 0; j < 4; ++j)
          acc[p][j] = __builtin_amdgcn_mfma_f32_16x16x32_bf16(af[p], bw[j], acc[p][j], 0, 0, 0);
    }

    // ---- epilogue: bias+relu, float4 stores (D: col=l15, row=l4*4+r)
    float bias[4];
    #pragma unroll
    for (int j = 0; j < 4; ++j) bias[j] = b2[j * 16 + l15];
    #pragma unroll
    for (int p = 0; p < 2; ++p) {
      int mt = 2 * w + p;
      int yv = y0 + (mt >> 2);
      int xb = ((mt & 3) << 4) + l4 * 4;
      if (xb <= 52) {
        #pragma unroll
        for (int j = 0; j < 4; ++j) {
          int oc = j * 16 + l15;
          float4 v;
          v.x = fmaxf(acc[p][j][0] + bias[j], 0.f);
          v.y = fmaxf(acc[p][j][1] + bias[j], 0.f);
          v.z = fmaxf(acc[p][j][2] + bias[j], 0.f);
          v.w = fmaxf(acc[p][j][3] + bias[j], 0.f);
          *(float4*)&h2[(size_t)(b * C2 + oc) * (H2 * W2) + yv * W2 + xb] = v;
        }
      }
    }
}

// ---------------- global average pool: (64,64,56,56) -> feat (64,64) ----------
__global__ __launch_bounds__(256) void pool_kernel(const float* __restrict__ h2,
        float* __restrict__ feat) {
    int bc = blockIdx.x;                             // 0..4095 = b*64 + c
    const float* p = h2 + (size_t)bc * (H2 * W2);
    float s = 0.f;
    for (int i = threadIdx.x; i < H2 * W2; i += 256) s += p[i];
    #pragma unroll
    for (int off = 32; off; off >>= 1) s += __shfl_down(s, off);
    __shared__ float red[4];
    if ((threadIdx.x & 63) == 0) red[threadIdx.x >> 6] = s;
    __syncthreads();
    if (threadIdx.x == 0)
      feat[bc] = (red[0] + red[1] + red[2] + red[3]) * (1.f / (H2 * W2));
}

// ---------------- center: fc = feat - rowmean(feat) ---------------------------
__global__ __launch_bounds__(64) void center_kernel(const float* __restrict__ feat,
        float* __restrict__ fc) {
    __shared__ float fl[FEATN * FEATN];
    int t = threadIdx.x;                             // 64 threads; t = b
    for (int i = t; i < FEATN * FEATN; i += 64) fl[i] = feat[i];
    __syncthreads();
    float m = 0.f;
    for (int c = 0; c < FEATN; ++c) m += fl[t*FEATN + c];
    m *= (1.f / FEATN);
    for (int c = 0; c < FEATN; ++c) fc[t*FEATN + c] = fl[t*FEATN + c] - m;
}

// -------- mean_feat + cov_feat + all biases -> WRITES d_out -------------------
__global__ __launch_bounds__(256) void meancov_kernel(const float* __restrict__ feat,
        const float* __restrict__ fc,
        const float* __restrict__ wm, const float* __restrict__ bm,
        const float* __restrict__ wc, const float* __restrict__ bcv,
        const float* __restrict__ b3, float* __restrict__ out) {
    __shared__ float featT[FEATN * FEATN];           // [c][b]
    __shared__ float fcT[FEATN * FEATN];             // [c][b]
    int t = threadIdx.x;
    for (int i = t; i < FEATN * FEATN; i += 256) {
      int b = i >> 6, c = i & 63;
      featT[c*64 + b] = feat[i];
      fcT[c*64 + b]   = fc[i];
    }
    __syncthreads();

    int b = t & 63;
    int o = blockIdx.x * 4 + (t >> 6);               // 256 blocks * 4 = 1024

    float fr[64];                                    // fc[b][*] in registers
    #pragma unroll
    for (int c4 = 0; c4 < 16; ++c4) {
      float4 v = *(const float4*)(fc + b*64 + c4*4);
      fr[c4*4+0]=v.x; fr[c4*4+1]=v.y; fr[c4*4+2]=v.z; fr[c4*4+3]=v.w;
    }

    float acc = bm[o] + bcv[o] + b3[o];
    #pragma unroll 8
    for (int c = 0; c < FEATN; ++c)
      acc = fmaf(featT[c*64 + b], wm[o*FEATN + c], acc);

    const float* wcrow = wc + (size_t)o * (FEATN * FEATN);
    #pragma unroll 1
    for (int c1 = 0; c1 < 64; ++c1) {
      float a2 = 0.f;
      #pragma unroll
      for (int c2 = 0; c2 < 64; ++c2)                // fr[c2]: static index
        a2 = fmaf(fr[c2], wcrow[c1*64 + c2], a2);
      acc = fmaf(fcT[c1*64 + b], a2, acc);           // LDS: 64 reads total
    }
    out[b * OUTN + o] = acc;
}

// -------- third-order term: C[b,o] += sum_ijk fc_i fc_j fc_k * w3[o,ijk] ------
// CHUNK_IJ=4: 1 KB contiguous per column per chunk; each global_load_lds inst
// covers exactly ONE column (64 lanes x 16 B), 16-B XOR swizzle pre-applied to
// the SOURCE (linear LDS dest, swizzled read). Counted vmcnt(16), dbuf,
// no barriers in the K-loop (per-wave-private columns).
#define T3_NBLK 32
#define KSLICES 128
#define CHUNK_IJ 4
#define NCHUNK 8            // 32 ij-pairs / CHUNK_IJ
#define T3_GRID (T3_NBLK * KSLICES)

struct T3Shared {
    float stage[2][32][CHUNK_IJ*64];   // [buf][block-col][k]  (64 KB)
    float fcJ[32][65];                 // fc[b][jbase+jl] as [jl][b], padded
    float fcI[64];                     // fc[b][i0]
};

__device__ __forceinline__ void t3_issue(const char* w3b, float (*buf)[CHUNK_IJ*64],
        int wave, int ocolbase, size_t kb, int lane) {
    int lo = lane * 16;                 // byte within the column's 1 KB chunk
    #pragma unroll
    for (int i = 0; i < 16; ++i) {
      int col = wave * 16 + i;          // block-local column of this inst
      // inverse-swizzle the SOURCE so a swizzled READ sees w3[col][kb+koff]
      int srcoff = lo ^ ((col & 7) << 4);
      const char* src = w3b + (((size_t)(ocolbase + col)) << 20) + kb + srcoff;
      gload_lds16(src, &buf[col][0]);
    }
}

__device__ __forceinline__ void t3_compute(const float (*buf)[CHUNK_IJ*64],
        const float (*fcJ)[65], const float* fcI,
        int c, int wave, int lane, const float4 aA[4][2], const float4 aB[4][2],
        f32x4 acc[4]) {
    int l15 = lane & 15, l4 = lane >> 4;
    int col = wave*16 + l15;
    int swz = (col & 7) << 4;
    int x0 = (l4*32) ^ swz;
    int x1 = (l4*32 + 16) ^ swz;
    const char* p = (const char*)&buf[col][0];
    #pragma unroll
    for (int e = 0; e < CHUNK_IJ; ++e) {
      int jl = c*CHUNK_IJ + e;
      float smul[4];
      #pragma unroll
      for (int m = 0; m < 4; ++m) {
        int bb = m*16 + l15;
        smul[m] = fcI[bb] * fcJ[jl][bb];
      }
      #pragma unroll
      for (int s = 0; s < 2; ++s) {
        int K = e*256 + s*128;                       // static after unroll
        float4 b0 = *(const float4*)(p + K + x0);
        float4 b1 = *(const float4*)(p + K + x1);
        bf16x8 bfrag;
        bfrag[0] = (__bf16)b0.x; bfrag[1] = (__bf16)b0.y;
        bfrag[2] = (__bf16)b0.z; bfrag[3] = (__bf16)b0.w;
        bfrag[4] = (__bf16)b1.x; bfrag[5] = (__bf16)b1.y;
        bfrag[6] = (__bf16)b1.z; bfrag[7] = (__bf16)b1.w;
        #pragma unroll
        for (int m = 0; m < 4; ++m) {
          float sc = smul[m];
          bf16x8 afrag;
          afrag[0] = (__bf16)(aA[m][s].x * sc); afrag[1] = (__bf16)(aA[m][s].y * sc);
          afrag[2] = (__bf16)(aA[m][s].z * sc); afrag[3] = (__bf16)(aA[m][s].w * sc);
          afrag[4] = (__bf16)(aB[m][s].x * sc); afrag[5] = (__bf16)(aB[m][s].y * sc);
          afrag[6] = (__bf16)(aB[m][s].z * sc); afrag[7] = (__bf16)(aB[m][s].w * sc);
          acc[m] = __builtin_amdgcn_mfma_f32_16x16x32_bf16(afrag, bfrag, acc[m], 0, 0, 0);
        }
      }
    }
}

#define T3_WAIT(N) do { asm volatile("s_waitcnt vmcnt(" #N ")" ::: "memory"); \
                        __builtin_amdgcn_sched_barrier(0); } while (0)

__global__ __launch_bounds__(128) void third_kernel(const float* __restrict__ fc,
        const float* __restrict__ w3, float* __restrict__ part) {
    __shared__ T3Shared sh;
    int t = threadIdx.x;
    int nblk   = blockIdx.x & (T3_NBLK - 1);
    int kslice = blockIdx.x >> 5;
    int i0     = kslice >> 1;                        // i is constant per kslice
    int jbase  = (kslice & 1) * 32;

    // stage fcJ (transposed, padded) and fcI
    for (int idx = t; idx < 32*64; idx += 128) {
      int b = idx >> 5, jl = idx & 31;               // contiguous 32-float reads
      sh.fcJ[jl][b] = fc[b*64 + jbase + jl];
    }
    if (t < 64) sh.fcI[t] = fc[t*64 + i0];
    __syncthreads();                                 // drains vmcnt too

    int wave = t >> 6;
    int lane = t & 63;
    int l15  = lane & 15;
    int l4   = lane >> 4;
    int ocolbase = nblk * 32;

    // Hoisted raw A fragments: fc[m*16+l15][(s*4+l4)*8 .. +8)
    float4 aA[4][2], aB[4][2];
    #pragma unroll
    for (int m = 0; m < 4; ++m)
      #pragma unroll
      for (int s = 0; s < 2; ++s) {
        const float* pa = fc + (m*16 + l15)*64 + (s*4 + l4)*8;
        aA[m][s] = *(const float4*)pa;
        aB[m][s] = *(const float4*)(pa + 4);
      }

    f32x4 acc[4];
    #pragma unroll
    for (int m = 0; m < 4; ++m) acc[m] = (f32x4){0.f, 0.f, 0.f, 0.f};

    const char* w3b = (const char*)w3;
    size_t kb0 = (size_t)kslice * 8192;              // byte offset within column
    #define KB(c) (kb0 + (size_t)(c) * (CHUNK_IJ*64*4))

    t3_issue(w3b, sh.stage[0], wave, ocolbase, KB(0), lane);
    #pragma unroll 1
    for (int c = 0; c < NCHUNK - 2; c += 2) {
      t3_issue(w3b, sh.stage[1], wave, ocolbase, KB(c+1), lane);
      T3_WAIT(16);
      t3_compute(sh.stage[0], sh.fcJ, sh.fcI, c, wave, lane, aA, aB, acc);
      t3_issue(w3b, sh.stage[0], wave, ocolbase, KB(c+2), lane);
      T3_WAIT(16);
      t3_compute(sh.stage[1], sh.fcJ, sh.fcI, c+1, wave, lane, aA, aB, acc);
    }
    t3_issue(w3b, sh.stage[1], wave, ocolbase, KB(NCHUNK-1), lane);
    T3_WAIT(16);
    t3_compute(sh.stage[0], sh.fcJ, sh.fcI, NCHUNK-2, wave, lane, aA, aB, acc);
    T3_WAIT(0);
    t3_compute(sh.stage[1], sh.fcJ, sh.fcI, NCHUNK-1, wave, lane, aA, aB, acc);

    // D layout (verified m89): col = lane&15, row = (lane>>4)*4 + reg
    float* pt = part + (size_t)kslice * 64 * OUTN;
    int ocol = ocolbase + wave*16 + l15;
    #pragma unroll
    for (int m = 0; m < 4; ++m)
      #pragma unroll
      for (int r = 0; r < 4; ++r) {
        int row = m*16 + l4*4 + r;                   // batch
        pt[row * OUTN + ocol] = acc[m][r];
      }
}

// -------- sum the 128 K-slice partials into d_out ------------------------------
__global__ __launch_bounds__(256) void reduce_kernel(const float* __restrict__ part,
        float* __restrict__ out) {
    int idx = blockIdx.x * 256 + threadIdx.x;        // 65536 = 64*1024
    float s = 0.f;
    #pragma unroll 8
    for (int ks = 0; ks < KSLICES; ++ks)
      s += part[(size_t)ks * (64 * OUTN) + idx];
    out[idx] += s;
}

extern "C" void kernel_launch(void* const* d_in, const int* in_sizes, int n_in,
                              void* d_out, int out_size, void* d_ws, size_t ws_size,
                              hipStream_t stream) {
    const float* x   = (const float*)d_in[0];
    const float* w1  = (const float*)d_in[1];
    const float* b1  = (const float*)d_in[2];
    const float* w2  = (const float*)d_in[3];
    const float* b2  = (const float*)d_in[4];
    const float* wm  = (const float*)d_in[5];
    const float* bm  = (const float*)d_in[6];
    const float* wc  = (const float*)d_in[7];
    const float* bcv = (const float*)d_in[8];
    const float* w3  = (const float*)d_in[9];
    const float* b3  = (const float*)d_in[10];
    float* out = (float*)d_out;

    // workspace layout (float offsets):
    //   h1T (bf16, 26,615,808 elems = 13,307,904 f) | h2 | feat | fc | part | w2frag
    float* ws    = (float*)d_ws;
    __bf16* h1T  = (__bf16*)ws;                      // 53.2 MB
    float* h2    = ws + 13307904;                    // 12,845,056 floats
    float* feat  = ws + 26152960;                    // 4096
    float* fcv   = ws + 26157056;                    // 4096
    float* part  = ws + 26161152;                    // 8,388,608
    __bf16* wfrg = (__bf16*)(ws + 34549760);         // 18,432 bf16

    halo_kernel  <<<113,  256, 0, stream>>>(h1T);
    w2frag_kernel<<<72,   256, 0, stream>>>(w2, wfrg);
    conv1_kernel <<<3136, 256, 0, stream>>>(x, w1, b1, h1T);
    conv2_kernel <<<1792, 256, 0, stream>>>(h1T, wfrg, b2, h2);
    pool_kernel  <<<4096, 256, 0, stream>>>(h2, feat);
    center_kernel<<<1,    64,  0, stream>>>(feat, fcv);
    meancov_kernel<<<256, 256, 0, stream>>>(feat, fcv, wm, bm, wc, bcv, b3, out);
    third_kernel <<<T3_GRID, 128, 0, stream>>>(fcv, w3, part);
    reduce_kernel<<<256,  256, 0, stream>>>(part, out);
}

// Round 9
// 408.880 us; speedup vs baseline: 1.0436x; 1.0436x over previous
//
#include <hip/hip_runtime.h>
#include <hip/hip_bf16.h>

// Problem constants
#define BB   64
#define CIN  3
#define HH   224
#define WW   224
#define C1   32
#define H1   112
#define W1   112
#define C2   64
#define H2   56
#define W2   56
#define FEATN 64
#define OUTN 1024
#define K3TOT (FEATN*FEATN*FEATN)   // 262144

typedef __bf16 bf16x8 __attribute__((ext_vector_type(8)));
typedef float  f32x4  __attribute__((ext_vector_type(4)));
typedef unsigned int u32;

__device__ __forceinline__ void gload_lds16(const void* g, void* l) {
  __builtin_amdgcn_global_load_lds((const __attribute__((address_space(1))) u32*)g,
                                   (__attribute__((address_space(3))) u32*)l, 16, 0, 0);
}

// ---- halo: zero the 1-px border ring of h1T (64 x 114 x 114 x 32 bf16) ------
__global__ __launch_bounds__(256) void halo_kernel(__bf16* __restrict__ h1T) {
    int t = blockIdx.x * 256 + threadIdx.x;          // 64*452 = 28928
    if (t >= 64 * 452) return;
    int b = t / 452, s = t - b * 452;
    int row, col;
    if      (s < 114) { row = 0;        col = s; }
    else if (s < 228) { row = 113;      col = s - 114; }
    else if (s < 340) { row = s - 227;  col = 0; }     // rows 1..112
    else              { row = s - 339;  col = 113; }   // rows 1..112
    __bf16* p = h1T + (((size_t)b * 114 + row) * 114 + col) * 32;
    bf16x8 z = {};
    #pragma unroll
    for (int k = 0; k < 4; ++k) *(bf16x8*)(p + k * 8) = z;
}

// ---- w2frag: B-fragment-ready bf16 layout [j][q][lane][8] --------------------
__global__ __launch_bounds__(256) void w2frag_kernel(const float* __restrict__ w2,
        __bf16* __restrict__ wf) {
    int t = blockIdx.x * 256 + threadIdx.x;          // 18432
    if (t >= 4 * 9 * 64 * 8) return;
    int e    = t & 7;
    int lane = (t >> 3) & 63;
    int q    = (t >> 9) % 9;
    int j    = t / 4608;
    int oc = j * 16 + (lane & 15);
    int c  = (lane >> 4) * 8 + e;
    wf[t] = (__bf16)w2[(oc * C1 + c) * 9 + q];
}

// ---------------- conv1: (64,3,224,224) -> relu -> h1T channels-last bf16 -----
__global__ __launch_bounds__(256) void conv1_kernel(const float* __restrict__ x,
        const float* __restrict__ w1, const float* __restrict__ b1,
        __bf16* __restrict__ h1T) {
    int pos = blockIdx.x * 256 + threadIdx.x;        // 64*112*112 = 802816
    int b   = pos / (H1 * W1);
    int rem = pos - b * (H1 * W1);
    int oy  = rem / W1;
    int ox  = rem - oy * W1;
    int iy0 = oy * 2 - 1, ix0 = ox * 2 - 1;

    float win[27];
    #pragma unroll
    for (int c = 0; c < CIN; ++c)
      #pragma unroll
      for (int dy = 0; dy < 3; ++dy)
        #pragma unroll
        for (int dx = 0; dx < 3; ++dx) {
          int iy = iy0 + dy, ix = ix0 + dx;
          bool ok = (iy >= 0) & (iy < HH) & (ix >= 0) & (ix < WW);
          win[c*9 + dy*3 + dx] = ok ? x[((b*CIN + c)*HH + iy)*WW + ix] : 0.f;
        }

    float acc[32];
    #pragma unroll
    for (int oc = 0; oc < C1; ++oc) acc[oc] = b1[oc];
    #pragma unroll
    for (int q = 0; q < 27; ++q) {
      float wv = win[q];
      #pragma unroll
      for (int oc = 0; oc < C1; ++oc)
        acc[oc] = fmaf(w1[oc*27 + q], wv, acc[oc]);
    }

    bf16x8 outv[4];
    #pragma unroll
    for (int k = 0; k < 32; ++k)
      outv[k >> 3][k & 7] = (__bf16)fmaxf(acc[k], 0.f);
    __bf16* dst = h1T + (((size_t)b * 114 + oy + 1) * 114 + ox + 1) * 32;
    #pragma unroll
    for (int k = 0; k < 4; ++k) *(bf16x8*)(dst + k * 8) = outv[k];
}

// ------ conv2 + fused global-avg-pool: implicit-GEMM MFMA, partials out -------
// Block: 256 thr (4 waves) = 1 image x 2 output rows x 64 x (8 pad) x 64 oc.
// Epilogue: relu in-register, mask padding lanes, shfl-reduce over x, write
// per-tile pooled partials featp[yt][b][oc]. NO h2 materialization.
__global__ __launch_bounds__(256) void conv2_kernel(const __bf16* __restrict__ h1T,
        const __bf16* __restrict__ wf, const float* __restrict__ b2,
        float* __restrict__ featp) {
    __shared__ __align__(16) char tile[2304 * 16];   // 36864 B (2280 real + pad)
    __shared__ float pool_red[4][64];
    int t = threadIdx.x;
    int bid = blockIdx.x;                            // 64*28 = 1792
    int b  = bid / 28;
    int yt = bid - b * 28;
    int y0 = yt * 2;
    int w = t >> 6, lane = t & 63, l15 = lane & 15, l4 = lane >> 4;

    // ---- stage 5x114 sites (64B each) via gload_lds, 9 issues/wave
    const char* src_base = (const char*)(h1T + ((size_t)b * 114 + 2 * y0) * 114 * 32);
    #pragma unroll
    for (int i = 0; i < 9; ++i) {
      int g = (w * 9 + i) * 64 + lane;
      int site = g >> 2; site = site < 569 ? site : 569;
      int qp = g & 3;
      int r5 = site / 114;
      int col = site - r5 * 114;
      int ql = (qp - col) & 3;
      gload_lds16(src_base + (size_t)site * 64 + ql * 16, tile + (size_t)g * 16);
    }
    __syncthreads();

    // per-wave output tiles: mt = 2w+p, p in {0,1}
    int sbase[2], urot[2];
    #pragma unroll
    for (int p = 0; p < 2; ++p) {
      int mt = 2 * w + p;
      int yl = mt >> 2;
      int xl = ((mt & 3) << 4) + l15;
      int xe = xl < 55 ? xl : 55;                    // clamp padding lanes
      sbase[p] = ((yl * 2) * 114 + 2 * xe) * 64;
      urot[p]  = (l4 + 2 * xe) & 3;
    }

    f32x4 acc[2][4];
    #pragma unroll
    for (int p = 0; p < 2; ++p)
      #pragma unroll
      for (int j = 0; j < 4; ++j) acc[p][j] = (f32x4){0.f, 0.f, 0.f, 0.f};

    #pragma unroll
    for (int q = 0; q < 9; ++q) {
      int dy = q / 3, dx = q % 3;
      bf16x8 bw[4];
      #pragma unroll
      for (int j = 0; j < 4; ++j)
        bw[j] = *(const bf16x8*)(wf + ((j * 9 + q) * 64 + lane) * 8);
      bf16x8 af[2];
      #pragma unroll
      for (int p = 0; p < 2; ++p) {
        int addr = sbase[p] + (dy * 114 + dx) * 64 + (((urot[p] + dx) & 3) << 4);
        af[p] = *(const bf16x8*)(tile + addr);
      }
      #pragma unroll
      for (int p = 0; p < 2; ++p)
        #pragma unroll
        for (int j = 0; j < 4; ++j)
          acc[p][j] = __builtin_amdgcn_mfma_f32_16x16x32_bf16(af[p], bw[j], acc[p][j], 0, 0, 0);
    }

    // ---- epilogue: fused pooling. D: col(oc)=l15 (+j*16), x = (mt&3)*16+l4*4+r
    float bias[4];
    #pragma unroll
    for (int j = 0; j < 4; ++j) bias[j] = b2[j * 16 + l15];
    float ps[4] = {0.f, 0.f, 0.f, 0.f};
    #pragma unroll
    for (int p = 0; p < 2; ++p) {
      int mt = 2 * w + p;
      bool valid = ((mt & 3) != 3) || (l4 < 2);      // x<56 mask
      #pragma unroll
      for (int j = 0; j < 4; ++j) {
        float sj = 0.f;
        #pragma unroll
        for (int r = 0; r < 4; ++r)
          sj += fmaxf(acc[p][j][r] + bias[j], 0.f);
        ps[j] += valid ? sj : 0.f;
      }
    }
    #pragma unroll
    for (int j = 0; j < 4; ++j) {
      ps[j] += __shfl_xor(ps[j], 16);
      ps[j] += __shfl_xor(ps[j], 32);
    }
    if (l4 == 0) {
      #pragma unroll
      for (int j = 0; j < 4; ++j) pool_red[w][j * 16 + l15] = ps[j];
    }
    __syncthreads();
    if (t < 64) {
      float s = pool_red[0][t] + pool_red[1][t] + pool_red[2][t] + pool_red[3][t];
      featp[((size_t)yt * 64 + b) * 64 + t] = s;
    }
}

// ---- center2: featN = (sum_yt featp)/3136; fc = featN - rowmean(featN) -------
__global__ __launch_bounds__(64) void center2_kernel(const float* __restrict__ featp,
        float* __restrict__ featN, float* __restrict__ fc) {
    int b = blockIdx.x;                              // 64 blocks (1 wave each)
    int c = threadIdx.x;
    float s = 0.f;
    #pragma unroll 7
    for (int yt = 0; yt < 28; ++yt)
      s += featp[((size_t)yt * 64 + b) * 64 + c];
    s *= (1.f / (H2 * W2));
    float tot = s;
    #pragma unroll
    for (int off = 32; off; off >>= 1) tot += __shfl_xor(tot, off);
    featN[b * 64 + c] = s;
    fc[b * 64 + c]    = s - tot * (1.f / 64.f);
}

// -------- mean_feat + cov_feat + all biases -> WRITES d_out -------------------
__global__ __launch_bounds__(256) void meancov_kernel(const float* __restrict__ feat,
        const float* __restrict__ fc,
        const float* __restrict__ wm, const float* __restrict__ bm,
        const float* __restrict__ wc, const float* __restrict__ bcv,
        const float* __restrict__ b3, float* __restrict__ out) {
    __shared__ float featT[FEATN * FEATN];           // [c][b]
    __shared__ float fcT[FEATN * FEATN];             // [c][b]
    int t = threadIdx.x;
    for (int i = t; i < FEATN * FEATN; i += 256) {
      int b = i >> 6, c = i & 63;
      featT[c*64 + b] = feat[i];
      fcT[c*64 + b]   = fc[i];
    }
    __syncthreads();

    int b = t & 63;
    int o = blockIdx.x * 4 + (t >> 6);               // 256 blocks * 4 = 1024

    float fr[64];                                    // fc[b][*] in registers
    #pragma unroll
    for (int c4 = 0; c4 < 16; ++c4) {
      float4 v = *(const float4*)(fc + b*64 + c4*4);
      fr[c4*4+0]=v.x; fr[c4*4+1]=v.y; fr[c4*4+2]=v.z; fr[c4*4+3]=v.w;
    }

    float acc = bm[o] + bcv[o] + b3[o];
    #pragma unroll 8
    for (int c = 0; c < FEATN; ++c)
      acc = fmaf(featT[c*64 + b], wm[o*FEATN + c], acc);

    const float* wcrow = wc + (size_t)o * (FEATN * FEATN);
    #pragma unroll 1
    for (int c1 = 0; c1 < 64; ++c1) {
      float a2 = 0.f;
      #pragma unroll
      for (int c2 = 0; c2 < 64; ++c2)                // fr[c2]: static index
        a2 = fmaf(fr[c2], wcrow[c1*64 + c2], a2);
      acc = fmaf(fcT[c1*64 + b], a2, acc);           // LDS: 64 reads total
    }
    out[b * OUTN + o] = acc;
}

// -------- third-order term: C[b,o] += sum_ijk fc_i fc_j fc_k * w3[o,ijk] ------
// R7 config (CHUNK_IJ=2) + dispatch remap: consecutive blockIdx share the same
// 32-column group (nblk = bid>>7), walking kslices -> concentrated DRAM footprint.
#define T3_NBLK 32
#define KSLICES 128
#define CHUNK_IJ 2
#define NCHUNK 16           // 32 ij-pairs / CHUNK_IJ
#define T3_GRID (T3_NBLK * KSLICES)

struct T3Shared {
    float stage[2][32][CHUNK_IJ*64];   // [buf][block-col][k]  (32 KB)
    float fcJ[32][65];                 // fc[b][jbase+jl] as [jl][b], padded
    float fcI[64];                     // fc[b][i0]
};

__device__ __forceinline__ void t3_issue(const char* w3b, float (*buf)[CHUNK_IJ*64],
        int wave, int ocolbase, size_t kb, int lane) {
    int hi = lane >> 5;                 // which of the 2 cols this lane feeds
    int lo = (lane & 31) * 16;          // byte within the column's 512-B span
    #pragma unroll
    for (int i = 0; i < 8; ++i) {
      int colb = wave*16 + 2*i;         // block-local col of this inst (even)
      int col  = colb + hi;
      // inverse-swizzle the SOURCE so a swizzled READ sees w3[col][kb+koff]
      int srcoff = lo ^ ((col & 7) << 4);
      const char* src = w3b + (((size_t)(ocolbase + col)) << 20) + kb + srcoff;
      gload_lds16(src, &buf[colb][0]);
    }
}

__device__ __forceinline__ void t3_compute(const float (*buf)[CHUNK_IJ*64],
        const float (*fcJ)[65], const float* fcI,
        int c, int wave, int lane, const float4 aA[4][2], const float4 aB[4][2],
        f32x4 acc[4]) {
    int l15 = lane & 15, l4 = lane >> 4;
    int col = wave*16 + l15;
    int swz = (col & 7) << 4;
    int x0 = (l4*32) ^ swz;
    int x1 = (l4*32 + 16) ^ swz;
    const char* p = (const char*)&buf[col][0];
    #pragma unroll
    for (int e = 0; e < CHUNK_IJ; ++e) {
      int jl = c*CHUNK_IJ + e;
      float smul[4];
      #pragma unroll
      for (int m = 0; m < 4; ++m) {
        int bb = m*16 + l15;
        smul[m] = fcI[bb] * fcJ[jl][bb];
      }
      #pragma unroll
      for (int s = 0; s < 2; ++s) {
        int K = e*256 + s*128;                       // static after unroll
        float4 b0 = *(const float4*)(p + K + x0);
        float4 b1 = *(const float4*)(p + K + x1);
        bf16x8 bfrag;
        bfrag[0] = (__bf16)b0.x; bfrag[1] = (__bf16)b0.y;
        bfrag[2] = (__bf16)b0.z; bfrag[3] = (__bf16)b0.w;
        bfrag[4] = (__bf16)b1.x; bfrag[5] = (__bf16)b1.y;
        bfrag[6] = (__bf16)b1.z; bfrag[7] = (__bf16)b1.w;
        #pragma unroll
        for (int m = 0; m < 4; ++m) {
          float sc = smul[m];
          bf16x8 afrag;
          afrag[0] = (__bf16)(aA[m][s].x * sc); afrag[1] = (__bf16)(aA[m][s].y * sc);
          afrag[2] = (__bf16)(aA[m][s].z * sc); afrag[3] = (__bf16)(aA[m][s].w * sc);
          afrag[4] = (__bf16)(aB[m][s].x * sc); afrag[5] = (__bf16)(aB[m][s].y * sc);
          afrag[6] = (__bf16)(aB[m][s].z * sc); afrag[7] = (__bf16)(aB[m][s].w * sc);
          acc[m] = __builtin_amdgcn_mfma_f32_16x16x32_bf16(afrag, bfrag, acc[m], 0, 0, 0);
        }
      }
    }
}

#define T3_WAIT(N) do { asm volatile("s_waitcnt vmcnt(" #N ")" ::: "memory"); \
                        __builtin_amdgcn_sched_barrier(0); } while (0)

__global__ __launch_bounds__(128) void third_kernel(const float* __restrict__ fc,
        const float* __restrict__ w3, float* __restrict__ part) {
    __shared__ T3Shared sh;
    int t = threadIdx.x;
    int nblk   = blockIdx.x >> 7;                    // REMAP: cols grouped
    int kslice = blockIdx.x & 127;                   //   consecutive bids: kslices
    int i0     = kslice >> 1;                        // i is constant per kslice
    int jbase  = (kslice & 1) * 32;

    // stage fcJ (transposed, padded) and fcI
    for (int idx = t; idx < 32*64; idx += 128) {
      int b = idx >> 5, jl = idx & 31;               // contiguous 32-float reads
      sh.fcJ[jl][b] = fc[b*64 + jbase + jl];
    }
    if (t < 64) sh.fcI[t] = fc[t*64 + i0];
    __syncthreads();                                 // drains vmcnt too

    int wave = t >> 6;
    int lane = t & 63;
    int l15  = lane & 15;
    int l4   = lane >> 4;
    int ocolbase = nblk * 32;

    // Hoisted raw A fragments: fc[m*16+l15][(s*4+l4)*8 .. +8)
    float4 aA[4][2], aB[4][2];
    #pragma unroll
    for (int m = 0; m < 4; ++m)
      #pragma unroll
      for (int s = 0; s < 2; ++s) {
        const float* pa = fc + (m*16 + l15)*64 + (s*4 + l4)*8;
        aA[m][s] = *(const float4*)pa;
        aB[m][s] = *(const float4*)(pa + 4);
      }

    f32x4 acc[4];
    #pragma unroll
    for (int m = 0; m < 4; ++m) acc[m] = (f32x4){0.f, 0.f, 0.f, 0.f};

    const char* w3b = (const char*)w3;
    size_t kb0 = (size_t)kslice * 8192;              // byte offset within column
    #define KB(c) (kb0 + (size_t)(c) * (CHUNK_IJ*64*4))

    t3_issue(w3b, sh.stage[0], wave, ocolbase, KB(0), lane);
    #pragma unroll 1
    for (int c = 0; c < NCHUNK - 2; c += 2) {
      t3_issue(w3b, sh.stage[1], wave, ocolbase, KB(c+1), lane);
      T3_WAIT(8);
      t3_compute(sh.stage[0], sh.fcJ, sh.fcI, c, wave, lane, aA, aB, acc);
      t3_issue(w3b, sh.stage[0], wave, ocolbase, KB(c+2), lane);
      T3_WAIT(8);
      t3_compute(sh.stage[1], sh.fcJ, sh.fcI, c+1, wave, lane, aA, aB, acc);
    }
    t3_issue(w3b, sh.stage[1], wave, ocolbase, KB(NCHUNK-1), lane);
    T3_WAIT(8);
    t3_compute(sh.stage[0], sh.fcJ, sh.fcI, NCHUNK-2, wave, lane, aA, aB, acc);
    T3_WAIT(0);
    t3_compute(sh.stage[1], sh.fcJ, sh.fcI, NCHUNK-1, wave, lane, aA, aB, acc);

    // D layout (verified m89): col = lane&15, row = (lane>>4)*4 + reg
    float* pt = part + (size_t)kslice * 64 * OUTN;
    int ocol = ocolbase + wave*16 + l15;
    #pragma unroll
    for (int m = 0; m < 4; ++m)
      #pragma unroll
      for (int r = 0; r < 4; ++r) {
        int row = m*16 + l4*4 + r;                   // batch
        pt[row * OUTN + ocol] = acc[m][r];
      }
}

// -------- sum the 128 K-slice partials into d_out ------------------------------
__global__ __launch_bounds__(256) void reduce_kernel(const float* __restrict__ part,
        float* __restrict__ out) {
    int idx = blockIdx.x * 256 + threadIdx.x;        // 65536 = 64*1024
    float s = 0.f;
    #pragma unroll 8
    for (int ks = 0; ks < KSLICES; ++ks)
      s += part[(size_t)ks * (64 * OUTN) + idx];
    out[idx] += s;
}

extern "C" void kernel_launch(void* const* d_in, const int* in_sizes, int n_in,
                              void* d_out, int out_size, void* d_ws, size_t ws_size,
                              hipStream_t stream) {
    const float* x   = (const float*)d_in[0];
    const float* w1  = (const float*)d_in[1];
    const float* b1  = (const float*)d_in[2];
    const float* w2  = (const float*)d_in[3];
    const float* b2  = (const float*)d_in[4];
    const float* wm  = (const float*)d_in[5];
    const float* bm  = (const float*)d_in[6];
    const float* wc  = (const float*)d_in[7];
    const float* bcv = (const float*)d_in[8];
    const float* w3  = (const float*)d_in[9];
    const float* b3  = (const float*)d_in[10];
    float* out = (float*)d_out;

    // workspace layout (float offsets):
    //   h1T (bf16) | featp | featN | fc | part | w2frag   (~87 MB total)
    float* ws    = (float*)d_ws;
    __bf16* h1T  = (__bf16*)ws;                      // 26,615,808 bf16 = 53.2 MB
    float* featp = ws + 13307904;                    // 28*64*64 = 114,688
    float* featN = ws + 13422592;                    // 4096
    float* fcv   = ws + 13426688;                    // 4096
    float* part  = ws + 13430784;                    // 128*64*1024 = 8,388,608
    __bf16* wfrg = (__bf16*)(ws + 21819392);         // 18,432 bf16

    halo_kernel   <<<113,  256, 0, stream>>>(h1T);
    w2frag_kernel <<<72,   256, 0, stream>>>(w2, wfrg);
    conv1_kernel  <<<3136, 256, 0, stream>>>(x, w1, b1, h1T);
    conv2_kernel  <<<1792, 256, 0, stream>>>(h1T, wfrg, b2, featp);
    center2_kernel<<<64,   64,  0, stream>>>(featp, featN, fcv);
    meancov_kernel<<<256,  256, 0, stream>>>(featN, fcv, wm, bm, wc, bcv, b3, out);
    third_kernel  <<<T3_GRID, 128, 0, stream>>>(fcv, w3, part);
    reduce_kernel <<<256,  256, 0, stream>>>(part, out);
}

// Round 10
// 358.078 us; speedup vs baseline: 1.1917x; 1.1419x over previous
//
#include <hip/hip_runtime.h>
#include <hip/hip_bf16.h>

// Problem constants
#define BB   64
#define CIN  3
#define HH   224
#define WW   224
#define C1   32
#define H1   112
#define W1   112
#define C2   64
#define H2   56
#define W2   56
#define FEATN 64
#define OUTN 1024
#define K3TOT (FEATN*FEATN*FEATN)   // 262144

typedef __bf16 bf16x8 __attribute__((ext_vector_type(8)));
typedef float  f32x4  __attribute__((ext_vector_type(4)));
typedef unsigned int u32;

__device__ __forceinline__ void gload_lds16(const void* g, void* l) {
  __builtin_amdgcn_global_load_lds((const __attribute__((address_space(1))) u32*)g,
                                   (__attribute__((address_space(3))) u32*)l, 16, 0, 0);
}
// non-temporal variant for single-use streams (w3): aux=2 -> NT bit on gfx940+
__device__ __forceinline__ void gload_lds16_nt(const void* g, void* l) {
  __builtin_amdgcn_global_load_lds((const __attribute__((address_space(1))) u32*)g,
                                   (__attribute__((address_space(3))) u32*)l, 16, 0, 2);
}

// ---- prep: halo-zero h1T border + w2frag build (merged tiny kernels) ---------
__global__ __launch_bounds__(256) void prep_kernel(__bf16* __restrict__ h1T,
        const float* __restrict__ w2, __bf16* __restrict__ wf) {
    int gid = blockIdx.x * 256 + threadIdx.x;
    if (gid < 64 * 452) {                            // halo: 28928 threads
      int b = gid / 452, s = gid - b * 452;
      int row, col;
      if      (s < 114) { row = 0;        col = s; }
      else if (s < 228) { row = 113;      col = s - 114; }
      else if (s < 340) { row = s - 227;  col = 0; }
      else              { row = s - 339;  col = 113; }
      __bf16* p = h1T + (((size_t)b * 114 + row) * 114 + col) * 32;
      bf16x8 z = {};
      #pragma unroll
      for (int k = 0; k < 4; ++k) *(bf16x8*)(p + k * 8) = z;
    } else if (gid < 64 * 452 + 18432) {             // w2frag: 18432 threads
      int t = gid - 64 * 452;
      int e    = t & 7;
      int lane = (t >> 3) & 63;
      int q    = (t >> 9) % 9;
      int j    = t / 4608;
      int oc = j * 16 + (lane & 15);
      int c  = (lane >> 4) * 8 + e;
      wf[t] = (__bf16)w2[(oc * C1 + c) * 9 + q];
    }
}

// ---------------- conv1: 2 outputs/thread, float4 row loads -------------------
__global__ __launch_bounds__(256) void conv1_kernel(const float* __restrict__ x,
        const float* __restrict__ w1, const float* __restrict__ b1,
        __bf16* __restrict__ h1T) {
    int pos = blockIdx.x * 256 + threadIdx.x;        // 64*112*56 = 401408
    int b   = pos / (H1 * 56);
    int rem = pos - b * (H1 * 56);
    int oy  = rem / 56;
    int g   = rem - oy * 56;                         // x-pair group: ox = 2g+u
    int iy0 = oy * 2 - 1;

    // input window: rows iy0..iy0+2, cols 4g-1 .. 4g+3 (5 wide)
    float win[CIN][3][5];
    #pragma unroll
    for (int c = 0; c < CIN; ++c)
      #pragma unroll
      for (int dy = 0; dy < 3; ++dy) {
        int iy = iy0 + dy;
        bool rv = (iy >= 0) & (iy < HH);
        const float* row = x + ((size_t)(b * CIN + c) * HH + (rv ? iy : 0)) * WW;
        float lf = (rv && g > 0) ? row[4 * g - 1] : 0.f;
        float4 f4 = rv ? *(const float4*)(row + 4 * g) : (float4){0.f, 0.f, 0.f, 0.f};
        win[c][dy][0] = lf;
        win[c][dy][1] = f4.x; win[c][dy][2] = f4.y;
        win[c][dy][3] = f4.z; win[c][dy][4] = f4.w;
      }

    float acc[2][C1];
    #pragma unroll
    for (int u = 0; u < 2; ++u)
      #pragma unroll
      for (int oc = 0; oc < C1; ++oc) acc[u][oc] = b1[oc];

    #pragma unroll
    for (int c = 0; c < CIN; ++c)
      #pragma unroll
      for (int dy = 0; dy < 3; ++dy)
        #pragma unroll
        for (int dx = 0; dx < 3; ++dx) {
          float w0 = win[c][dy][dx];
          float w1v = win[c][dy][dx + 2];
          const float* wq = w1 + c * 9 + dy * 3 + dx;
          #pragma unroll
          for (int oc = 0; oc < C1; ++oc) {
            float wv = wq[oc * 27];
            acc[0][oc] = fmaf(wv, w0, acc[0][oc]);
            acc[1][oc] = fmaf(wv, w1v, acc[1][oc]);
          }
        }

    __bf16* dst = h1T + (((size_t)b * 114 + oy + 1) * 114 + (2 * g) + 1) * 32;
    #pragma unroll
    for (int u = 0; u < 2; ++u) {
      bf16x8 outv[4];
      #pragma unroll
      for (int k = 0; k < 32; ++k)
        outv[k >> 3][k & 7] = (__bf16)fmaxf(acc[u][k], 0.f);
      #pragma unroll
      for (int k = 0; k < 4; ++k) *(bf16x8*)(dst + u * 32 + k * 8) = outv[k];
    }
}

// ------ conv2 + fused global-avg-pool: implicit-GEMM MFMA, partials out -------
__global__ __launch_bounds__(256) void conv2_kernel(const __bf16* __restrict__ h1T,
        const __bf16* __restrict__ wf, const float* __restrict__ b2,
        float* __restrict__ featp) {
    __shared__ __align__(16) char tile[2304 * 16];   // 36864 B (2280 real + pad)
    __shared__ float pool_red[4][64];
    int t = threadIdx.x;
    int bid = blockIdx.x;                            // 64*28 = 1792
    int b  = bid / 28;
    int yt = bid - b * 28;
    int y0 = yt * 2;
    int w = t >> 6, lane = t & 63, l15 = lane & 15, l4 = lane >> 4;

    // ---- stage 5x114 sites (64B each) via gload_lds, 9 issues/wave
    const char* src_base = (const char*)(h1T + ((size_t)b * 114 + 2 * y0) * 114 * 32);
    #pragma unroll
    for (int i = 0; i < 9; ++i) {
      int g = (w * 9 + i) * 64 + lane;
      int site = g >> 2; site = site < 569 ? site : 569;
      int qp = g & 3;
      int r5 = site / 114;
      int col = site - r5 * 114;
      int ql = (qp - col) & 3;
      gload_lds16(src_base + (size_t)site * 64 + ql * 16, tile + (size_t)g * 16);
    }
    __syncthreads();

    int sbase[2], urot[2];
    #pragma unroll
    for (int p = 0; p < 2; ++p) {
      int mt = 2 * w + p;
      int yl = mt >> 2;
      int xl = ((mt & 3) << 4) + l15;
      int xe = xl < 55 ? xl : 55;                    // clamp padding lanes
      sbase[p] = ((yl * 2) * 114 + 2 * xe) * 64;
      urot[p]  = (l4 + 2 * xe) & 3;
    }

    f32x4 acc[2][4];
    #pragma unroll
    for (int p = 0; p < 2; ++p)
      #pragma unroll
      for (int j = 0; j < 4; ++j) acc[p][j] = (f32x4){0.f, 0.f, 0.f, 0.f};

    #pragma unroll
    for (int q = 0; q < 9; ++q) {
      int dy = q / 3, dx = q % 3;
      bf16x8 bw[4];
      #pragma unroll
      for (int j = 0; j < 4; ++j)
        bw[j] = *(const bf16x8*)(wf + ((j * 9 + q) * 64 + lane) * 8);
      bf16x8 af[2];
      #pragma unroll
      for (int p = 0; p < 2; ++p) {
        int addr = sbase[p] + (dy * 114 + dx) * 64 + (((urot[p] + dx) & 3) << 4);
        af[p] = *(const bf16x8*)(tile + addr);
      }
      #pragma unroll
      for (int p = 0; p < 2; ++p)
        #pragma unroll
        for (int j = 0; j < 4; ++j)
          acc[p][j] = __builtin_amdgcn_mfma_f32_16x16x32_bf16(af[p], bw[j], acc[p][j], 0, 0, 0);
    }

    // ---- epilogue: fused pooling
    float bias[4];
    #pragma unroll
    for (int j = 0; j < 4; ++j) bias[j] = b2[j * 16 + l15];
    float ps[4] = {0.f, 0.f, 0.f, 0.f};
    #pragma unroll
    for (int p = 0; p < 2; ++p) {
      int mt = 2 * w + p;
      bool valid = ((mt & 3) != 3) || (l4 < 2);      // x<56 mask
      #pragma unroll
      for (int j = 0; j < 4; ++j) {
        float sj = 0.f;
        #pragma unroll
        for (int r = 0; r < 4; ++r)
          sj += fmaxf(acc[p][j][r] + bias[j], 0.f);
        ps[j] += valid ? sj : 0.f;
      }
    }
    #pragma unroll
    for (int j = 0; j < 4; ++j) {
      ps[j] += __shfl_xor(ps[j], 16);
      ps[j] += __shfl_xor(ps[j], 32);
    }
    if (l4 == 0) {
      #pragma unroll
      for (int j = 0; j < 4; ++j) pool_red[w][j * 16 + l15] = ps[j];
    }
    __syncthreads();
    if (t < 64) {
      float s = pool_red[0][t] + pool_red[1][t] + pool_red[2][t] + pool_red[3][t];
      featp[((size_t)yt * 64 + b) * 64 + t] = s;
    }
}

// ---- center2: featN = (sum_yt featp)/3136; fc = featN - rowmean(featN) -------
__global__ __launch_bounds__(64) void center2_kernel(const float* __restrict__ featp,
        float* __restrict__ featN, float* __restrict__ fc) {
    int b = blockIdx.x;                              // 64 blocks (1 wave each)
    int c = threadIdx.x;
    float s = 0.f;
    #pragma unroll 7
    for (int yt = 0; yt < 28; ++yt)
      s += featp[((size_t)yt * 64 + b) * 64 + c];
    s *= (1.f / (H2 * W2));
    float tot = s;
    #pragma unroll
    for (int off = 32; off; off >>= 1) tot += __shfl_xor(tot, off);
    featN[b * 64 + c] = s;
    fc[b * 64 + c]    = s - tot * (1.f / 64.f);
}

// -------- third-order term: NT w3 streaming, transposed partials --------------
#define T3_NBLK 32
#define KSLICES 128
#define CHUNK_IJ 2
#define NCHUNK 16           // 32 ij-pairs / CHUNK_IJ
#define T3_GRID (T3_NBLK * KSLICES)

struct T3Shared {
    float stage[2][32][CHUNK_IJ*64];   // [buf][block-col][k]  (32 KB)
    float fcJ[32][65];                 // fc[b][jbase+jl] as [jl][b], padded
    float fcI[64];                     // fc[b][i0]
};

__device__ __forceinline__ void t3_issue(const char* w3b, float (*buf)[CHUNK_IJ*64],
        int wave, int ocolbase, size_t kb, int lane) {
    int hi = lane >> 5;                 // which of the 2 cols this lane feeds
    int lo = (lane & 31) * 16;          // byte within the column's 512-B span
    #pragma unroll
    for (int i = 0; i < 8; ++i) {
      int colb = wave*16 + 2*i;         // block-local col of this inst (even)
      int col  = colb + hi;
      // inverse-swizzle the SOURCE so a swizzled READ sees w3[col][kb+koff]
      int srcoff = lo ^ ((col & 7) << 4);
      const char* src = w3b + (((size_t)(ocolbase + col)) << 20) + kb + srcoff;
      gload_lds16_nt(src, &buf[colb][0]);
    }
}

__device__ __forceinline__ void t3_compute(const float (*buf)[CHUNK_IJ*64],
        const float (*fcJ)[65], const float* fcI,
        int c, int wave, int lane, const float4 aA[4][2], const float4 aB[4][2],
        f32x4 acc[4]) {
    int l15 = lane & 15, l4 = lane >> 4;
    int col = wave*16 + l15;
    int swz = (col & 7) << 4;
    int x0 = (l4*32) ^ swz;
    int x1 = (l4*32 + 16) ^ swz;
    const char* p = (const char*)&buf[col][0];
    #pragma unroll
    for (int e = 0; e < CHUNK_IJ; ++e) {
      int jl = c*CHUNK_IJ + e;
      float smul[4];
      #pragma unroll
      for (int m = 0; m < 4; ++m) {
        int bb = m*16 + l15;
        smul[m] = fcI[bb] * fcJ[jl][bb];
      }
      #pragma unroll
      for (int s = 0; s < 2; ++s) {
        int K = e*256 + s*128;                       // static after unroll
        float4 b0 = *(const float4*)(p + K + x0);
        float4 b1 = *(const float4*)(p + K + x1);
        bf16x8 bfrag;
        bfrag[0] = (__bf16)b0.x; bfrag[1] = (__bf16)b0.y;
        bfrag[2] = (__bf16)b0.z; bfrag[3] = (__bf16)b0.w;
        bfrag[4] = (__bf16)b1.x; bfrag[5] = (__bf16)b1.y;
        bfrag[6] = (__bf16)b1.z; bfrag[7] = (__bf16)b1.w;
        #pragma unroll
        for (int m = 0; m < 4; ++m) {
          float sc = smul[m];
          bf16x8 afrag;
          afrag[0] = (__bf16)(aA[m][s].x * sc); afrag[1] = (__bf16)(aA[m][s].y * sc);
          afrag[2] = (__bf16)(aA[m][s].z * sc); afrag[3] = (__bf16)(aA[m][s].w * sc);
          afrag[4] = (__bf16)(aB[m][s].x * sc); afrag[5] = (__bf16)(aB[m][s].y * sc);
          afrag[6] = (__bf16)(aB[m][s].z * sc); afrag[7] = (__bf16)(aB[m][s].w * sc);
          acc[m] = __builtin_amdgcn_mfma_f32_16x16x32_bf16(afrag, bfrag, acc[m], 0, 0, 0);
        }
      }
    }
}

#define T3_WAIT(N) do { asm volatile("s_waitcnt vmcnt(" #N ")" ::: "memory"); \
                        __builtin_amdgcn_sched_barrier(0); } while (0)

__global__ __launch_bounds__(128) void third_kernel(const float* __restrict__ fc,
        const float* __restrict__ w3, float* __restrict__ part) {
    __shared__ T3Shared sh;
    int t = threadIdx.x;
    int nblk   = blockIdx.x >> 7;                    // cols grouped; kslice walks
    int kslice = blockIdx.x & 127;
    int i0     = kslice >> 1;                        // i is constant per kslice
    int jbase  = (kslice & 1) * 32;

    // stage fcJ (transposed, padded) and fcI
    for (int idx = t; idx < 32*64; idx += 128) {
      int b = idx >> 5, jl = idx & 31;               // contiguous 32-float reads
      sh.fcJ[jl][b] = fc[b*64 + jbase + jl];
    }
    if (t < 64) sh.fcI[t] = fc[t*64 + i0];
    __syncthreads();                                 // drains vmcnt too

    int wave = t >> 6;
    int lane = t & 63;
    int l15  = lane & 15;
    int l4   = lane >> 4;
    int ocolbase = nblk * 32;

    // Hoisted raw A fragments: fc[m*16+l15][(s*4+l4)*8 .. +8)
    float4 aA[4][2], aB[4][2];
    #pragma unroll
    for (int m = 0; m < 4; ++m)
      #pragma unroll
      for (int s = 0; s < 2; ++s) {
        const float* pa = fc + (m*16 + l15)*64 + (s*4 + l4)*8;
        aA[m][s] = *(const float4*)pa;
        aB[m][s] = *(const float4*)(pa + 4);
      }

    f32x4 acc[4];
    #pragma unroll
    for (int m = 0; m < 4; ++m) acc[m] = (f32x4){0.f, 0.f, 0.f, 0.f};

    const char* w3b = (const char*)w3;
    size_t kb0 = (size_t)kslice * 8192;              // byte offset within column
    #define KB(c) (kb0 + (size_t)(c) * (CHUNK_IJ*64*4))

    t3_issue(w3b, sh.stage[0], wave, ocolbase, KB(0), lane);
    #pragma unroll 1
    for (int c = 0; c < NCHUNK - 2; c += 2) {
      t3_issue(w3b, sh.stage[1], wave, ocolbase, KB(c+1), lane);
      T3_WAIT(8);
      t3_compute(sh.stage[0], sh.fcJ, sh.fcI, c, wave, lane, aA, aB, acc);
      t3_issue(w3b, sh.stage[0], wave, ocolbase, KB(c+2), lane);
      T3_WAIT(8);
      t3_compute(sh.stage[1], sh.fcJ, sh.fcI, c+1, wave, lane, aA, aB, acc);
    }
    t3_issue(w3b, sh.stage[1], wave, ocolbase, KB(NCHUNK-1), lane);
    T3_WAIT(8);
    t3_compute(sh.stage[0], sh.fcJ, sh.fcI, NCHUNK-2, wave, lane, aA, aB, acc);
    T3_WAIT(0);
    t3_compute(sh.stage[1], sh.fcJ, sh.fcI, NCHUNK-1, wave, lane, aA, aB, acc);

    // transposed partials: part[ks][ocol][row], float4 stores (rows contiguous)
    float* pt = part + (size_t)kslice * 64 * OUTN;
    int ocol = ocolbase + wave*16 + l15;
    #pragma unroll
    for (int m = 0; m < 4; ++m) {
      float4 v = {acc[m][0], acc[m][1], acc[m][2], acc[m][3]};
      *(float4*)&pt[(size_t)ocol * 64 + m * 16 + l4 * 4] = v;
    }
}

// ---- finale: mean_feat + cov_feat + biases + third partials -> d_out ---------
__global__ __launch_bounds__(256) void finale_kernel(const float* __restrict__ feat,
        const float* __restrict__ fc,
        const float* __restrict__ wm, const float* __restrict__ bm,
        const float* __restrict__ wc, const float* __restrict__ bcv,
        const float* __restrict__ b3, const float* __restrict__ part,
        float* __restrict__ out) {
    __shared__ float featT[FEATN * FEATN];           // [c][b]
    __shared__ float fcT[FEATN * FEATN];             // [c][b]
    int t = threadIdx.x;
    for (int i = t; i < FEATN * FEATN; i += 256) {
      int b = i >> 6, c = i & 63;
      featT[c*64 + b] = feat[i];
      fcT[c*64 + b]   = fc[i];
    }
    __syncthreads();

    int b = t & 63;
    int o = blockIdx.x * 4 + (t >> 6);               // 256 blocks * 4 = 1024

    float fr[64];                                    // fc[b][*] in registers
    #pragma unroll
    for (int c4 = 0; c4 < 16; ++c4) {
      float4 v = *(const float4*)(fc + b*64 + c4*4);
      fr[c4*4+0]=v.x; fr[c4*4+1]=v.y; fr[c4*4+2]=v.z; fr[c4*4+3]=v.w;
    }

    float acc = bm[o] + bcv[o] + b3[o];
    #pragma unroll 8
    for (int c = 0; c < FEATN; ++c)
      acc = fmaf(featT[c*64 + b], wm[o*FEATN + c], acc);

    const float* wcrow = wc + (size_t)o * (FEATN * FEATN);
    #pragma unroll 1
    for (int c1 = 0; c1 < 64; ++c1) {
      float a2 = 0.f;
      #pragma unroll
      for (int c2 = 0; c2 < 64; ++c2)                // fr[c2]: static index
        a2 = fmaf(fr[c2], wcrow[c1*64 + c2], a2);
      acc = fmaf(fcT[c1*64 + b], a2, acc);           // LDS: 64 reads total
    }

    // third partials: part[ks][o][b] -> 256B-coalesced per 64-lane group
    float s = 0.f;
    #pragma unroll 8
    for (int ks = 0; ks < KSLICES; ++ks)
      s += part[(size_t)ks * (64 * OUTN) + o * 64 + b];

    out[b * OUTN + o] = acc + s;
}

extern "C" void kernel_launch(void* const* d_in, const int* in_sizes, int n_in,
                              void* d_out, int out_size, void* d_ws, size_t ws_size,
                              hipStream_t stream) {
    const float* x   = (const float*)d_in[0];
    const float* w1  = (const float*)d_in[1];
    const float* b1  = (const float*)d_in[2];
    const float* w2  = (const float*)d_in[3];
    const float* b2  = (const float*)d_in[4];
    const float* wm  = (const float*)d_in[5];
    const float* bm  = (const float*)d_in[6];
    const float* wc  = (const float*)d_in[7];
    const float* bcv = (const float*)d_in[8];
    const float* w3  = (const float*)d_in[9];
    const float* b3  = (const float*)d_in[10];
    float* out = (float*)d_out;

    // workspace layout (float offsets):
    //   h1T (bf16) | featp | featN | fc | part | w2frag   (~87 MB total)
    float* ws    = (float*)d_ws;
    __bf16* h1T  = (__bf16*)ws;                      // 26,615,808 bf16 = 53.2 MB
    float* featp = ws + 13307904;                    // 28*64*64 = 114,688
    float* featN = ws + 13422592;                    // 4096
    float* fcv   = ws + 13426688;                    // 4096
    float* part  = ws + 13430784;                    // 128*64*1024 = 8,388,608
    __bf16* wfrg = (__bf16*)(ws + 21819392);         // 18,432 bf16

    prep_kernel   <<<185,  256, 0, stream>>>(h1T, w2, wfrg);
    conv1_kernel  <<<1568, 256, 0, stream>>>(x, w1, b1, h1T);
    conv2_kernel  <<<1792, 256, 0, stream>>>(h1T, wfrg, b2, featp);
    center2_kernel<<<64,   64,  0, stream>>>(featp, featN, fcv);
    third_kernel  <<<T3_GRID, 128, 0, stream>>>(fcv, w3, part);
    finale_kernel <<<256,  256, 0, stream>>>(featN, fcv, wm, bm, wc, bcv, b3, part, out);
}

// Round 11
// 295.517 us; speedup vs baseline: 1.4440x; 1.2117x over previous
//
#include <hip/hip_runtime.h>
#include <hip/hip_bf16.h>

// Problem constants
#define BB   64
#define CIN  3
#define HH   224
#define WW   224
#define C1   32
#define H1   112
#define W1   112
#define C2   64
#define H2   56
#define W2   56
#define FEATN 64
#define OUTN 1024
#define K3TOT (FEATN*FEATN*FEATN)   // 262144

typedef __bf16 bf16x8 __attribute__((ext_vector_type(8)));
typedef float  f32x4  __attribute__((ext_vector_type(4)));
typedef unsigned int u32;

__device__ __forceinline__ void gload_lds16(const void* g, void* l) {
  __builtin_amdgcn_global_load_lds((const __attribute__((address_space(1))) u32*)g,
                                   (__attribute__((address_space(3))) u32*)l, 16, 0, 0);
}
// non-temporal variant for single-use streams (w3)
__device__ __forceinline__ void gload_lds16_nt(const void* g, void* l) {
  __builtin_amdgcn_global_load_lds((const __attribute__((address_space(1))) u32*)g,
                                   (__attribute__((address_space(3))) u32*)l, 16, 0, 2);
}

// ---- prep: halo-zero h1T border + w2frag build --------------------------------
__global__ __launch_bounds__(256) void prep_kernel(__bf16* __restrict__ h1T,
        const float* __restrict__ w2, __bf16* __restrict__ wf) {
    int gid = blockIdx.x * 256 + threadIdx.x;
    if (gid < 64 * 452) {                            // halo: 28928 threads
      int b = gid / 452, s = gid - b * 452;
      int row, col;
      if      (s < 114) { row = 0;        col = s; }
      else if (s < 228) { row = 113;      col = s - 114; }
      else if (s < 340) { row = s - 227;  col = 0; }
      else              { row = s - 339;  col = 113; }
      __bf16* p = h1T + (((size_t)b * 114 + row) * 114 + col) * 32;
      bf16x8 z = {};
      #pragma unroll
      for (int k = 0; k < 4; ++k) *(bf16x8*)(p + k * 8) = z;
    } else if (gid < 64 * 452 + 18432) {             // w2frag: 18432 threads
      int t = gid - 64 * 452;
      int e    = t & 7;
      int lane = (t >> 3) & 63;
      int q    = (t >> 9) % 9;
      int j    = t / 4608;
      int oc = j * 16 + (lane & 15);
      int c  = (lane >> 4) * 8 + e;
      wf[t] = (__bf16)w2[(oc * C1 + c) * 9 + q];
    }
}

// ---------------- conv1: 2 outputs/thread, float4 row loads -------------------
__global__ __launch_bounds__(256) void conv1_kernel(const float* __restrict__ x,
        const float* __restrict__ w1, const float* __restrict__ b1,
        __bf16* __restrict__ h1T) {
    int pos = blockIdx.x * 256 + threadIdx.x;        // 64*112*56 = 401408
    int b   = pos / (H1 * 56);
    int rem = pos - b * (H1 * 56);
    int oy  = rem / 56;
    int g   = rem - oy * 56;                         // x-pair group: ox = 2g+u
    int iy0 = oy * 2 - 1;

    float win[CIN][3][5];
    #pragma unroll
    for (int c = 0; c < CIN; ++c)
      #pragma unroll
      for (int dy = 0; dy < 3; ++dy) {
        int iy = iy0 + dy;
        bool rv = (iy >= 0) & (iy < HH);
        const float* row = x + ((size_t)(b * CIN + c) * HH + (rv ? iy : 0)) * WW;
        float lf = (rv && g > 0) ? row[4 * g - 1] : 0.f;
        float4 f4 = rv ? *(const float4*)(row + 4 * g) : (float4){0.f, 0.f, 0.f, 0.f};
        win[c][dy][0] = lf;
        win[c][dy][1] = f4.x; win[c][dy][2] = f4.y;
        win[c][dy][3] = f4.z; win[c][dy][4] = f4.w;
      }

    float acc[2][C1];
    #pragma unroll
    for (int u = 0; u < 2; ++u)
      #pragma unroll
      for (int oc = 0; oc < C1; ++oc) acc[u][oc] = b1[oc];

    #pragma unroll
    for (int c = 0; c < CIN; ++c)
      #pragma unroll
      for (int dy = 0; dy < 3; ++dy)
        #pragma unroll
        for (int dx = 0; dx < 3; ++dx) {
          float w0 = win[c][dy][dx];
          float w1v = win[c][dy][dx + 2];
          const float* wq = w1 + c * 9 + dy * 3 + dx;
          #pragma unroll
          for (int oc = 0; oc < C1; ++oc) {
            float wv = wq[oc * 27];
            acc[0][oc] = fmaf(wv, w0, acc[0][oc]);
            acc[1][oc] = fmaf(wv, w1v, acc[1][oc]);
          }
        }

    __bf16* dst = h1T + (((size_t)b * 114 + oy + 1) * 114 + (2 * g) + 1) * 32;
    #pragma unroll
    for (int u = 0; u < 2; ++u) {
      bf16x8 outv[4];
      #pragma unroll
      for (int k = 0; k < 32; ++k)
        outv[k >> 3][k & 7] = (__bf16)fmaxf(acc[u][k], 0.f);
      #pragma unroll
      for (int k = 0; k < 4; ++k) *(bf16x8*)(dst + u * 32 + k * 8) = outv[k];
    }
}

// ------ conv2 + fused global-avg-pool: implicit-GEMM MFMA, partials out -------
__global__ __launch_bounds__(256) void conv2_kernel(const __bf16* __restrict__ h1T,
        const __bf16* __restrict__ wf, const float* __restrict__ b2,
        float* __restrict__ featp) {
    __shared__ __align__(16) char tile[2304 * 16];   // 36864 B
    __shared__ float pool_red[4][64];
    int t = threadIdx.x;
    int bid = blockIdx.x;                            // 64*28 = 1792
    int b  = bid / 28;
    int yt = bid - b * 28;
    int y0 = yt * 2;
    int w = t >> 6, lane = t & 63, l15 = lane & 15, l4 = lane >> 4;

    const char* src_base = (const char*)(h1T + ((size_t)b * 114 + 2 * y0) * 114 * 32);
    #pragma unroll
    for (int i = 0; i < 9; ++i) {
      int g = (w * 9 + i) * 64 + lane;
      int site = g >> 2; site = site < 569 ? site : 569;
      int qp = g & 3;
      int r5 = site / 114;
      int col = site - r5 * 114;
      int ql = (qp - col) & 3;
      gload_lds16(src_base + (size_t)site * 64 + ql * 16, tile + (size_t)g * 16);
    }
    __syncthreads();

    int sbase[2], urot[2];
    #pragma unroll
    for (int p = 0; p < 2; ++p) {
      int mt = 2 * w + p;
      int yl = mt >> 2;
      int xl = ((mt & 3) << 4) + l15;
      int xe = xl < 55 ? xl : 55;
      sbase[p] = ((yl * 2) * 114 + 2 * xe) * 64;
      urot[p]  = (l4 + 2 * xe) & 3;
    }

    f32x4 acc[2][4];
    #pragma unroll
    for (int p = 0; p < 2; ++p)
      #pragma unroll
      for (int j = 0; j < 4; ++j) acc[p][j] = (f32x4){0.f, 0.f, 0.f, 0.f};

    #pragma unroll
    for (int q = 0; q < 9; ++q) {
      int dy = q / 3, dx = q % 3;
      bf16x8 bw[4];
      #pragma unroll
      for (int j = 0; j < 4; ++j)
        bw[j] = *(const bf16x8*)(wf + ((j * 9 + q) * 64 + lane) * 8);
      bf16x8 af[2];
      #pragma unroll
      for (int p = 0; p < 2; ++p) {
        int addr = sbase[p] + (dy * 114 + dx) * 64 + (((urot[p] + dx) & 3) << 4);
        af[p] = *(const bf16x8*)(tile + addr);
      }
      #pragma unroll
      for (int p = 0; p < 2; ++p)
        #pragma unroll
        for (int j = 0; j < 4; ++j)
          acc[p][j] = __builtin_amdgcn_mfma_f32_16x16x32_bf16(af[p], bw[j], acc[p][j], 0, 0, 0);
    }

    float bias[4];
    #pragma unroll
    for (int j = 0; j < 4; ++j) bias[j] = b2[j * 16 + l15];
    float ps[4] = {0.f, 0.f, 0.f, 0.f};
    #pragma unroll
    for (int p = 0; p < 2; ++p) {
      int mt = 2 * w + p;
      bool valid = ((mt & 3) != 3) || (l4 < 2);      // x<56 mask
      #pragma unroll
      for (int j = 0; j < 4; ++j) {
        float sj = 0.f;
        #pragma unroll
        for (int r = 0; r < 4; ++r)
          sj += fmaxf(acc[p][j][r] + bias[j], 0.f);
        ps[j] += valid ? sj : 0.f;
      }
    }
    #pragma unroll
    for (int j = 0; j < 4; ++j) {
      ps[j] += __shfl_xor(ps[j], 16);
      ps[j] += __shfl_xor(ps[j], 32);
    }
    if (l4 == 0) {
      #pragma unroll
      for (int j = 0; j < 4; ++j) pool_red[w][j * 16 + l15] = ps[j];
    }
    __syncthreads();
    if (t < 64) {
      float s = pool_red[0][t] + pool_red[1][t] + pool_red[2][t] + pool_red[3][t];
      featp[((size_t)yt * 64 + b) * 64 + t] = s;
    }
}

// ---- center2: featN = (sum_yt featp)/3136; fc = featN - rowmean(featN) -------
__global__ __launch_bounds__(64) void center2_kernel(const float* __restrict__ featp,
        float* __restrict__ featN, float* __restrict__ fc) {
    int b = blockIdx.x;                              // 64 blocks (1 wave each)
    int c = threadIdx.x;
    float s = 0.f;
    #pragma unroll 7
    for (int yt = 0; yt < 28; ++yt)
      s += featp[((size_t)yt * 64 + b) * 64 + c];
    s *= (1.f / (H2 * W2));
    float tot = s;
    #pragma unroll
    for (int off = 32; off; off >>= 1) tot += __shfl_xor(tot, off);
    featN[b * 64 + c] = s;
    fc[b * 64 + c]    = s - tot * (1.f / 64.f);
}

// -------- third-order term, ROW-STREAM design ----------------------------------
// One block per output column o. Block streams w3 row o (1 MB CONTIGUOUS);
// 2 waves x 512 KB halves, 4 KB chunks (16 ij x 64 k) via global_load_lds
// (pre-swizzled source, linear dest, swizzled read). Grid 1024 = 4 blocks/CU
// = exactly all-resident, single uniform pass, no tail.
// Math: v[ij,b] = sum_k w3[o,ij*64+k] fc[b,k]  (MFMA, B-frags in registers);
//       out[b]  = sum_ij fc_i[b] fc_j[b] v[ij,b]  (LDS fcT, padded 66).
#define T3_NCH 128          // chunks per wave (512KB / 4KB)

struct T3S {
    float stage[2][2][16][64];   // [wave][buf][ij][k]  32 KB
    float fcT[64][66];           // fcT[c][b], pad 66 -> bank-spread 16.9 KB
    float wred[2][64];
};

__global__ __launch_bounds__(128) void third_kernel(const float* __restrict__ fc,
        const float* __restrict__ w3, float* __restrict__ thrd) {
    __shared__ __align__(16) T3S sh;
    int t = threadIdx.x;
    int w = t >> 6, lane = t & 63, l15 = lane & 15, l4 = lane >> 4;
    int o = blockIdx.x;
    int swz = (l15 & 7) << 4;

    // stage fcT[c][b] = fc[b*64+c]
    for (int idx = t; idx < 4096; idx += 128)
      sh.fcT[idx & 63][idx >> 6] = fc[idx];

    const char* seg = (const char*)w3 + ((size_t)o << 20) + (size_t)w * 524288;

    // issue chunk 0 early (overlaps fcT staging + B-frag loads)
    #pragma unroll
    for (int ii = 0; ii < 4; ++ii) {
      int row = ii * 4 + (lane >> 4);
      int lo  = (lane & 15) * 16;
      gload_lds16_nt(seg + row * 256 + (lo ^ ((row & 7) << 4)),
                     (char*)&sh.stage[w][0][0][0] + ii * 1024);
    }

    // B-fragments in registers: bfrag[kstep][ntile] = fc[b=nt*16+l15][ks*32+l4*8+e]
    bf16x8 bfrag[2][4];
    #pragma unroll
    for (int ks = 0; ks < 2; ++ks)
      #pragma unroll
      for (int nt = 0; nt < 4; ++nt) {
        const float* p = fc + (nt * 16 + l15) * 64 + ks * 32 + l4 * 8;
        float4 v0 = *(const float4*)p;
        float4 v1 = *(const float4*)(p + 4);
        bfrag[ks][nt][0] = (__bf16)v0.x; bfrag[ks][nt][1] = (__bf16)v0.y;
        bfrag[ks][nt][2] = (__bf16)v0.z; bfrag[ks][nt][3] = (__bf16)v0.w;
        bfrag[ks][nt][4] = (__bf16)v1.x; bfrag[ks][nt][5] = (__bf16)v1.y;
        bfrag[ks][nt][6] = (__bf16)v1.z; bfrag[ks][nt][7] = (__bf16)v1.w;
      }

    __syncthreads();                                 // fcT ready (drains vmcnt too)

    float oacc[4] = {0.f, 0.f, 0.f, 0.f};

    #pragma unroll 1
    for (int c = 0; c < T3_NCH; ++c) {
      // issue chunk c+1 into the other buffer
      if (c + 1 < T3_NCH) {
        const char* s2 = seg + (size_t)(c + 1) * 4096;
        char* db = (char*)&sh.stage[w][(c + 1) & 1][0][0];
        #pragma unroll
        for (int ii = 0; ii < 4; ++ii) {
          int row = ii * 4 + (lane >> 4);
          int lo  = (lane & 15) * 16;
          gload_lds16_nt(s2 + row * 256 + (lo ^ ((row & 7) << 4)), db + ii * 1024);
        }
        asm volatile("s_waitcnt vmcnt(4)" ::: "memory");
      } else {
        asm volatile("s_waitcnt vmcnt(0)" ::: "memory");
      }
      __builtin_amdgcn_sched_barrier(0);

      // ---- compute chunk c
      const char* cb = (const char*)&sh.stage[w][c & 1][0][0];
      f32x4 acc[4];
      #pragma unroll
      for (int nt = 0; nt < 4; ++nt) acc[nt] = (f32x4){0.f, 0.f, 0.f, 0.f};
      #pragma unroll
      for (int ks = 0; ks < 2; ++ks) {
        int off0 = l15 * 256 + ((ks * 128 + l4 * 32) ^ swz);
        float4 a0 = *(const float4*)(cb + off0);
        float4 a1 = *(const float4*)(cb + (off0 ^ 16));
        bf16x8 af;
        af[0] = (__bf16)a0.x; af[1] = (__bf16)a0.y;
        af[2] = (__bf16)a0.z; af[3] = (__bf16)a0.w;
        af[4] = (__bf16)a1.x; af[5] = (__bf16)a1.y;
        af[6] = (__bf16)a1.z; af[7] = (__bf16)a1.w;
        #pragma unroll
        for (int nt = 0; nt < 4; ++nt)
          acc[nt] = __builtin_amdgcn_mfma_f32_16x16x32_bf16(af, bfrag[ks][nt], acc[nt], 0, 0, 0);
      }
      // contraction: out[b] += fi[b] * sum_r fj(r)[b] * v[r][b]
      int i = w * 32 + (c >> 2);                     // uniform within chunk
      #pragma unroll
      for (int nt = 0; nt < 4; ++nt) {
        int b = nt * 16 + l15;
        float s = 0.f;
        #pragma unroll
        for (int r = 0; r < 4; ++r) {
          int j = (c * 16 + l4 * 4 + r) & 63;
          s = fmaf(sh.fcT[j][b], acc[nt][r], s);
        }
        oacc[nt] = fmaf(sh.fcT[i][b], s, oacc[nt]);
      }
    }

    // reduce over l4 (rows), then over waves
    #pragma unroll
    for (int nt = 0; nt < 4; ++nt) {
      oacc[nt] += __shfl_xor(oacc[nt], 16);
      oacc[nt] += __shfl_xor(oacc[nt], 32);
    }
    if (l4 == 0) {
      #pragma unroll
      for (int nt = 0; nt < 4; ++nt) sh.wred[w][nt * 16 + l15] = oacc[nt];
    }
    __syncthreads();
    if (t < 64) thrd[o * 64 + t] = sh.wred[0][t] + sh.wred[1][t];
}

// ---- finale: mean_feat + cov_feat + biases + third -> d_out ------------------
__global__ __launch_bounds__(256) void finale_kernel(const float* __restrict__ feat,
        const float* __restrict__ fc,
        const float* __restrict__ wm, const float* __restrict__ bm,
        const float* __restrict__ wc, const float* __restrict__ bcv,
        const float* __restrict__ b3, const float* __restrict__ thrd,
        float* __restrict__ out) {
    __shared__ float featT[FEATN * FEATN];           // [c][b]
    __shared__ float fcT[FEATN * FEATN];             // [c][b]
    int t = threadIdx.x;
    for (int i = t; i < FEATN * FEATN; i += 256) {
      int b = i >> 6, c = i & 63;
      featT[c*64 + b] = feat[i];
      fcT[c*64 + b]   = fc[i];
    }
    __syncthreads();

    int b = t & 63;
    int o = blockIdx.x * 4 + (t >> 6);               // 256 blocks * 4 = 1024

    float fr[64];                                    // fc[b][*] in registers
    #pragma unroll
    for (int c4 = 0; c4 < 16; ++c4) {
      float4 v = *(const float4*)(fc + b*64 + c4*4);
      fr[c4*4+0]=v.x; fr[c4*4+1]=v.y; fr[c4*4+2]=v.z; fr[c4*4+3]=v.w;
    }

    float acc = bm[o] + bcv[o] + b3[o];
    #pragma unroll 8
    for (int c = 0; c < FEATN; ++c)
      acc = fmaf(featT[c*64 + b], wm[o*FEATN + c], acc);

    const float* wcrow = wc + (size_t)o * (FEATN * FEATN);
    #pragma unroll 1
    for (int c1 = 0; c1 < 64; ++c1) {
      float a2 = 0.f;
      #pragma unroll
      for (int c2 = 0; c2 < 64; ++c2)                // fr[c2]: static index
        a2 = fmaf(fr[c2], wcrow[c1*64 + c2], a2);
      acc = fmaf(fcT[c1*64 + b], a2, acc);
    }

    out[b * OUTN + o] = acc + thrd[o * 64 + b];
}

extern "C" void kernel_launch(void* const* d_in, const int* in_sizes, int n_in,
                              void* d_out, int out_size, void* d_ws, size_t ws_size,
                              hipStream_t stream) {
    const float* x   = (const float*)d_in[0];
    const float* w1  = (const float*)d_in[1];
    const float* b1  = (const float*)d_in[2];
    const float* w2  = (const float*)d_in[3];
    const float* b2  = (const float*)d_in[4];
    const float* wm  = (const float*)d_in[5];
    const float* bm  = (const float*)d_in[6];
    const float* wc  = (const float*)d_in[7];
    const float* bcv = (const float*)d_in[8];
    const float* w3  = (const float*)d_in[9];
    const float* b3  = (const float*)d_in[10];
    float* out = (float*)d_out;

    // workspace layout (float offsets):
    //   h1T (bf16) | featp | featN | fc | thrd | w2frag
    float* ws    = (float*)d_ws;
    __bf16* h1T  = (__bf16*)ws;                      // 26,615,808 bf16 = 53.2 MB
    float* featp = ws + 13307904;                    // 28*64*64 = 114,688
    float* featN = ws + 13422592;                    // 4096
    float* fcv   = ws + 13426688;                    // 4096
    float* thrd  = ws + 13430784;                    // 64*1024 = 65,536
    __bf16* wfrg = (__bf16*)(ws + 13496320);         // 18,432 bf16

    prep_kernel   <<<185,  256, 0, stream>>>(h1T, w2, wfrg);
    conv1_kernel  <<<1568, 256, 0, stream>>>(x, w1, b1, h1T);
    conv2_kernel  <<<1792, 256, 0, stream>>>(h1T, wfrg, b2, featp);
    center2_kernel<<<64,   64,  0, stream>>>(featp, featN, fcv);
    third_kernel  <<<1024, 128, 0, stream>>>(fcv, w3, thrd);
    finale_kernel <<<256,  256, 0, stream>>>(featN, fcv, wm, bm, wc, bcv, b3, thrd, out);
}